// Round 1
// baseline (251.975 us; speedup 1.0000x reference)
//
#include <hip/hip_runtime.h>

// filtfilt (4th-order IIR, 5-tap FIR) over 512 independent sequences of 48000.
// One 1024-thread block per sequence. V4: all __syncthreads() replaced by raw
// s_barrier + lgkmcnt(0)-only waits (m201 pattern). Rationale: __syncthreads
// emits s_waitcnt vmcnt(0) which (a) drains the pre-issued next-section global
// loads right after issue, defeating the prefetch, and (b) waits for store
// completion acks in the store-staging loop. vmcnt is per-wave and no wave
// consumes another wave's global data -> only lgkmcnt(0) ordering is required
// at barriers; the compiler still inserts counted vmcnt waits for each wave's
// own load consumption. Stores become fire-and-forget (kernel-end drain).
// __launch_bounds__(1024,8) pins VGPRs <= 64 to protect 2-blocks/CU residency.

#define T48 48000
#define TP0 48030      // padded true length (48000 + 2*15)
#define LCH 48
#define NCH 1024
#define UF  13344      // union region (floats): load-stage needs 13320

// lgkmcnt(0) + raw barrier: orders LDS ops across waves WITHOUT draining vmcnt.
// asm "memory" clobber = compiler-level fence so ds ops can't migrate across.
#define BAR_LDS() do { \
  asm volatile("s_waitcnt lgkmcnt(0)" ::: "memory"); \
  __builtin_amdgcn_s_barrier(); \
} while (0)

__device__ __forceinline__ float fget(const float4& v, int e) {
  switch (e & 3) { case 0: return v.x; case 1: return v.y; case 2: return v.z; default: return v.w; }
}

__global__ __launch_bounds__(1024, 8) void filtfilt_k(
    const float* __restrict__ x, const float* __restrict__ bco,
    const float* __restrict__ aco, float* __restrict__ out)
{
  __shared__ __align__(16) float U[UF];
  __shared__ float P[10][16];             // P[k] = M^(2^k), row-major 4x4

  const int c = threadIdx.x;
  const float* __restrict__ xs = x + (size_t)blockIdx.x * T48;
  const float4* __restrict__ xs4 = reinterpret_cast<const float4*>(xs);
  float* __restrict__ os = out + (size_t)blockIdx.x * T48;
  float4* __restrict__ os4 = reinterpret_cast<float4*>(os);
  float4* __restrict__ U4 = reinterpret_cast<float4*>(U);

  const float inva0 = 1.f / aco[0];
  const float b0 = bco[0]*inva0, b1 = bco[1]*inva0, b2 = bco[2]*inva0,
              b3 = bco[3]*inva0, b4 = bco[4]*inva0;
  const float na1 = -aco[1]*inva0, na2 = -aco[2]*inva0,
              na3 = -aco[3]*inva0, na4 = -aco[4]*inva0;

  // ---------- pre-issue global loads for section 0
  float4 R[4];
#pragma unroll
  for (int j = 0; j < 4; j++) {
    int g = 1024*j + c;
    if (g < 3074) { int m = min(max(g - 5, 0), 11999); R[j] = xs4[m]; }
  }

  // ---------- prologue (wave 0 only, shuffle-synchronous)
  if (c < 64) {
    const int i = (c >> 2) & 3, j = c & 3;
    float r1 = (j==0)?1.f:0.f, r2 = (j==1)?1.f:0.f,
          r3 = (j==2)?1.f:0.f, r4 = (j==3)?1.f:0.f;
#pragma unroll
    for (int n = 0; n < LCH; n++) {
      float h = fmaf(na1, r1, fmaf(na2, r2, fmaf(na3, r3, na4 * r4)));
      r4 = r3; r3 = r2; r2 = r1; r1 = h;
    }
    float c0 = __shfl(r1, j), c1 = __shfl(r2, j),
          c2 = __shfl(r3, j), c3 = __shfl(r4, j);
    float Pv = (i==0)?c0 : (i==1)?c1 : (i==2)?c2 : c3;
    if (c < 16) P[0][c] = Pv;
#pragma unroll
    for (int k = 0; k < 9; k++) {
      float rA0 = __shfl(Pv, i*4+0), rA1 = __shfl(Pv, i*4+1),
            rA2 = __shfl(Pv, i*4+2), rA3 = __shfl(Pv, i*4+3);
      float cB0 = __shfl(Pv, 0*4+j), cB1 = __shfl(Pv, 1*4+j),
            cB2 = __shfl(Pv, 2*4+j), cB3 = __shfl(Pv, 3*4+j);
      Pv = rA0*cB0 + rA1*cB1 + rA2*cB2 + rA3*cB3;
      if (c < 16) P[k+1][c] = Pv;
    }
  }

  // ---------- staged load: global float4 g lands at stage float4 g
  // stage float4 g holds padded p = 12288*s - 5 + 4g + e
  float w4v, w3v, w2v, w1v;
  float A[LCH];
  for (int s = 0; s < 4; s++) {
    BAR_LDS();                 // extraction reads of s-1 retired before overwrite
#pragma unroll
    for (int j = 0; j < 4; j++) {
      int g = 1024*j + c;
      if (g < 3074) {
        float4 v = R[j];
        bool slow = (s == 0 && g <= 4) || (s == 3 && g >= 2789);
        if (slow) {
          float x0d = 2.f * xs[0], xld = 2.f * xs[T48-1];
#pragma unroll
          for (int e = 0; e < 4; e++) {
            int p = 12288*s - 5 + 4*g + e;
            float vv = 0.f;
            if (s == 0) { if (p >= 0) vv = x0d - xs[14 - p]; }
            else        { if (p < TP0) vv = xld - xs[96012 - p]; }
            if (e == 0) v.x = vv; else if (e == 1) v.y = vv;
            else if (e == 2) v.z = vv; else v.w = vv;
          }
        }
        U4[g + g/12] = v;
      }
    }
    if (s < 3) {   // pre-issue next section — now actually stays in flight
#pragma unroll
      for (int j = 0; j < 4; j++) {
        int g = 1024*j + c;
        if (g < 3074) { int m = min(max(3072*(s+1) - 5 + g, 0), 11999); R[j] = xs4[m]; }
      }
    }
    BAR_LDS();                 // publish staged LDS writes (no vmcnt drain!)
    if ((c >> 8) == s) {
      const int cl = c & 255;
      float4 F[14];
#pragma unroll
      for (int k = 0; k < 14; k++)
        F[k] = U4[13*cl + k + (k >= 12 ? 1 : 0)];
      w4v = F[0].y; w3v = F[0].z; w2v = F[0].w; w1v = F[1].x;
#pragma unroll
      for (int n = 0; n < LCH; n++) A[n] = fget(F[(n + 5) >> 2], (n + 5) & 3);
    }
  }
  BAR_LDS();   // extraction reads done before scan overwrites U

  // ---------- forward phase 1 (in place, zero-state)
  float r1 = 0.f, r2 = 0.f, r3 = 0.f, r4 = 0.f;
#pragma unroll
  for (int n = 0; n < LCH; n++) {
    float xv = A[n];
    float f = fmaf(b0,xv, fmaf(b1,w1v, fmaf(b2,w2v, fmaf(b3,w3v, b4*w4v))));
    w4v = w3v; w3v = w2v; w2v = w1v; w1v = xv;
    float u = fmaf(na4, r4, f);
    u = fmaf(na3, r3, u); u = fmaf(na2, r2, u); u = fmaf(na1, r1, u);
    A[n] = u; r4 = r3; r3 = r2; r2 = r1; r1 = u;
  }

  // ---------- forward chunk-scan (ping-pong float4)
  float4* Sb0 = U4;
  float4* Sb1 = U4 + 1024;
  Sb0[c] = make_float4(r1, r2, r3, r4);
  BAR_LDS();
#pragma unroll
  for (int k = 0; k < 10; k++) {
    float4* cur = (k & 1) ? Sb1 : Sb0;
    float4* nxt = (k & 1) ? Sb0 : Sb1;
    const int off = 1 << k;
    float4 t = cur[c];
    if (c >= off) {
      float4 q = cur[c - off];
      t.x += P[k][0]*q.x  + P[k][1]*q.y  + P[k][2]*q.z  + P[k][3]*q.w;
      t.y += P[k][4]*q.x  + P[k][5]*q.y  + P[k][6]*q.z  + P[k][7]*q.w;
      t.z += P[k][8]*q.x  + P[k][9]*q.y  + P[k][10]*q.z + P[k][11]*q.w;
      t.w += P[k][12]*q.x + P[k][13]*q.y + P[k][14]*q.z + P[k][15]*q.w;
    }
    nxt[c] = t;
    BAR_LDS();
  }
  float4 sv = make_float4(0.f,0.f,0.f,0.f);
  if (c > 0) sv = Sb0[c-1];

  // ---------- forward phase 2: homogeneous correction
  {
    float h1 = sv.x, h2 = sv.y, h3 = sv.z, h4 = sv.w;
#pragma unroll
    for (int n = 0; n < LCH; n++) {
      float h = fmaf(na1, h1, fmaf(na2, h2, fmaf(na3, h3, na4 * h4)));
      A[n] += h;
      h4 = h3; h3 = h2; h2 = h1; h1 = h;
    }
  }
  // exact zero tail past TP0
  if (c >= 1000) {
#pragma unroll
    for (int n = 0; n < LCH; n++) if (48*c + n >= TP0) A[n] = 0.f;
  }

  // ---------- exchange heads (backward FIR halo)
  Sb1[c] = make_float4(A[0], A[1], A[2], A[3]);
  BAR_LDS();
  float h0 = 0.f, h1v = 0.f, h2v = 0.f, h3v = 0.f;
  if (c < NCH - 1) { float4 hv = Sb1[c+1]; h0 = hv.x; h1v = hv.y; h2v = hv.z; h3v = hv.w; }

  // ---------- backward phase 1 (own chunk reversed, in place)
#define YV(i) ((i) < 48 ? A[(i)] : ((i)==48 ? h0 : (i)==49 ? h1v : (i)==50 ? h2v : h3v))
  r1 = 0.f; r2 = 0.f; r3 = 0.f; r4 = 0.f;
#pragma unroll
  for (int m = 0; m < LCH; m++) {
    float g = fmaf(b0, YV(47-m), fmaf(b1, YV(48-m),
              fmaf(b2, YV(49-m), fmaf(b3, YV(50-m), b4 * YV(51-m)))));
    float u = fmaf(na4, r4, g);
    u = fmaf(na3, r3, u); u = fmaf(na2, r2, u); u = fmaf(na1, r1, u);
    r4 = r3; r3 = r2; r2 = r1; r1 = u;
    if      (m == 0) h3v = u;
    else if (m == 1) h2v = u;
    else if (m == 2) h1v = u;
    else if (m == 3) h0  = u;
    else             A[51 - m] = u;
  }
#undef YV
  // z[0]=h3v z[1]=h2v z[2]=h1v z[3]=h0 ; z[m]=A[51-m] for m>=4

  // ---------- backward chunk-scan
  const int d = NCH - 1 - c;
  Sb0[d] = make_float4(r1, r2, r3, r4);
  BAR_LDS();
#pragma unroll
  for (int k = 0; k < 10; k++) {
    float4* cur = (k & 1) ? Sb1 : Sb0;
    float4* nxt = (k & 1) ? Sb0 : Sb1;
    const int off = 1 << k;
    float4 t = cur[d];
    if (d >= off) {
      float4 q = cur[d - off];
      t.x += P[k][0]*q.x  + P[k][1]*q.y  + P[k][2]*q.z  + P[k][3]*q.w;
      t.y += P[k][4]*q.x  + P[k][5]*q.y  + P[k][6]*q.z  + P[k][7]*q.w;
      t.z += P[k][8]*q.x  + P[k][9]*q.y  + P[k][10]*q.z + P[k][11]*q.w;
      t.w += P[k][12]*q.x + P[k][13]*q.y + P[k][14]*q.z + P[k][15]*q.w;
    }
    nxt[d] = t;
    BAR_LDS();
  }
  float4 ev = make_float4(0.f,0.f,0.f,0.f);
  if (d > 0) ev = Sb0[d-1];

  // ---------- backward phase 2
  {
    float g1 = ev.x, g2 = ev.y, g3 = ev.z, g4 = ev.w;
#pragma unroll
    for (int m = 0; m < LCH; m++) {
      float h = fmaf(na1, g1, fmaf(na2, g2, fmaf(na3, g3, na4 * g4)));
      if      (m == 0) h3v += h;
      else if (m == 1) h2v += h;
      else if (m == 2) h1v += h;
      else if (m == 3) h0  += h;
      else             A[51 - m] += h;
      g4 = g3; g3 = g2; g2 = g1; g1 = h;
    }
  }

  // ---------- store staging: u = t + 3; thread c owns u4 in [12c-3, 12c+9)
  // slot k4 (u4 = 12c-3+k4) = (z[47-4k4], z[46-4k4], z[45-4k4], z[44-4k4])
  //   = (A[4k4+4..4k4+7]) for k4<=10 ; k4==11 -> (h0, h1v, h2v, h3v)
  BAR_LDS();   // ev reads retired before store-stage writes
  for (int s = 0; s < 4; s++) {
#pragma unroll
    for (int k4 = 0; k4 < 12; k4++) {
      int u4 = 12*c - 3 + k4;
      unsigned lu4 = (unsigned)(u4 - 3000*s);
      if (lu4 <= 3000u) {
        float4 v;
        if (k4 < 11) v = make_float4(A[4*k4+4], A[4*k4+5], A[4*k4+6], A[4*k4+7]);
        else         v = make_float4(h0, h1v, h2v, h3v);
        U4[(int)lu4 + (int)lu4/12] = v;
      }
    }
    BAR_LDS();                 // publish stage writes
#pragma unroll
    for (int j = 0; j < 3; j++) {
      int t4l = 1024*j + c;
      if (t4l < 3000) {
        int q0 = t4l, q1 = t4l + 1;
        int a0 = 4*(q0 + q0/12) + 3;
        int bi = 4*(q1 + q1/12);
        float4 v;
        v.x = U[a0]; v.y = U[bi]; v.z = U[bi+1]; v.w = U[bi+2];
        os4[3000*s + t4l] = v;   // fire-and-forget: no vmcnt wait, ever
      }
    }
    if (s < 3) BAR_LDS();      // readback ds_reads retired before next stage
  }
}

extern "C" void kernel_launch(void* const* d_in, const int* in_sizes, int n_in,
                              void* d_out, int out_size, void* d_ws, size_t ws_size,
                              hipStream_t stream) {
  (void)n_in; (void)d_ws; (void)ws_size; (void)out_size;
  const float* x = (const float*)d_in[0];
  const float* b = (const float*)d_in[1];
  const float* a = (const float*)d_in[2];
  float* out = (float*)d_out;
  const int nseq = in_sizes[0] / T48;   // 512
  filtfilt_k<<<dim3(nseq), dim3(1024), 0, stream>>>(x, b, a, out);
}

// Round 2
// 205.799 us; speedup vs baseline: 1.2244x; 1.2244x over previous
//
#include <hip/hip_runtime.h>

// filtfilt (4th-order IIR, 5-tap FIR) over 512 independent sequences of 48000.
// One 1024-thread block per sequence. V5 = V4's lgkmcnt-only barriers, with
// launch bounds reverted to (1024,4): V4's (1024,8) forced VGPRs down to 32,
// spilling A[48] to scratch (FETCH 48->150 MB, WRITE 96->300 MB, 3x HBM
// traffic). At 56 VGPR the kernel already fits 2 blocks/CU (LDS 54272B x2 <
// 160KiB, 56<=64 VGPR) -- no pin needed.
// Barriers: raw s_barrier + s_waitcnt lgkmcnt(0) only (m201 pattern) so the
// pre-issued next-section global loads stay in flight across barriers and
// global stores are fire-and-forget; vmcnt is per-wave and no wave consumes
// another wave's global data, so LDS ordering is all a barrier must provide.

#define T48 48000
#define TP0 48030      // padded true length (48000 + 2*15)
#define LCH 48
#define NCH 1024
#define UF  13344      // union region (floats): load-stage needs 13320

// lgkmcnt(0) + raw barrier: orders LDS ops across waves WITHOUT draining vmcnt.
// asm "memory" clobber = compiler-level fence so ds ops can't migrate across.
#define BAR_LDS() do { \
  asm volatile("s_waitcnt lgkmcnt(0)" ::: "memory"); \
  __builtin_amdgcn_s_barrier(); \
} while (0)

__device__ __forceinline__ float fget(const float4& v, int e) {
  switch (e & 3) { case 0: return v.x; case 1: return v.y; case 2: return v.z; default: return v.w; }
}

__global__ __launch_bounds__(1024, 4) void filtfilt_k(
    const float* __restrict__ x, const float* __restrict__ bco,
    const float* __restrict__ aco, float* __restrict__ out)
{
  __shared__ __align__(16) float U[UF];
  __shared__ float P[10][16];             // P[k] = M^(2^k), row-major 4x4

  const int c = threadIdx.x;
  const float* __restrict__ xs = x + (size_t)blockIdx.x * T48;
  const float4* __restrict__ xs4 = reinterpret_cast<const float4*>(xs);
  float* __restrict__ os = out + (size_t)blockIdx.x * T48;
  float4* __restrict__ os4 = reinterpret_cast<float4*>(os);
  float4* __restrict__ U4 = reinterpret_cast<float4*>(U);

  const float inva0 = 1.f / aco[0];
  const float b0 = bco[0]*inva0, b1 = bco[1]*inva0, b2 = bco[2]*inva0,
              b3 = bco[3]*inva0, b4 = bco[4]*inva0;
  const float na1 = -aco[1]*inva0, na2 = -aco[2]*inva0,
              na3 = -aco[3]*inva0, na4 = -aco[4]*inva0;

  // ---------- pre-issue global loads for section 0
  float4 R[4];
#pragma unroll
  for (int j = 0; j < 4; j++) {
    int g = 1024*j + c;
    if (g < 3074) { int m = min(max(g - 5, 0), 11999); R[j] = xs4[m]; }
  }

  // ---------- prologue (wave 0 only, shuffle-synchronous)
  if (c < 64) {
    const int i = (c >> 2) & 3, j = c & 3;
    float r1 = (j==0)?1.f:0.f, r2 = (j==1)?1.f:0.f,
          r3 = (j==2)?1.f:0.f, r4 = (j==3)?1.f:0.f;
#pragma unroll
    for (int n = 0; n < LCH; n++) {
      float h = fmaf(na1, r1, fmaf(na2, r2, fmaf(na3, r3, na4 * r4)));
      r4 = r3; r3 = r2; r2 = r1; r1 = h;
    }
    float c0 = __shfl(r1, j), c1 = __shfl(r2, j),
          c2 = __shfl(r3, j), c3 = __shfl(r4, j);
    float Pv = (i==0)?c0 : (i==1)?c1 : (i==2)?c2 : c3;
    if (c < 16) P[0][c] = Pv;
#pragma unroll
    for (int k = 0; k < 9; k++) {
      float rA0 = __shfl(Pv, i*4+0), rA1 = __shfl(Pv, i*4+1),
            rA2 = __shfl(Pv, i*4+2), rA3 = __shfl(Pv, i*4+3);
      float cB0 = __shfl(Pv, 0*4+j), cB1 = __shfl(Pv, 1*4+j),
            cB2 = __shfl(Pv, 2*4+j), cB3 = __shfl(Pv, 3*4+j);
      Pv = rA0*cB0 + rA1*cB1 + rA2*cB2 + rA3*cB3;
      if (c < 16) P[k+1][c] = Pv;
    }
  }

  // ---------- staged load: global float4 g lands at stage float4 g
  // stage float4 g holds padded p = 12288*s - 5 + 4g + e
  float w4v, w3v, w2v, w1v;
  float A[LCH];
  for (int s = 0; s < 4; s++) {
    BAR_LDS();                 // extraction reads of s-1 retired before overwrite
#pragma unroll
    for (int j = 0; j < 4; j++) {
      int g = 1024*j + c;
      if (g < 3074) {
        float4 v = R[j];
        bool slow = (s == 0 && g <= 4) || (s == 3 && g >= 2789);
        if (slow) {
          float x0d = 2.f * xs[0], xld = 2.f * xs[T48-1];
#pragma unroll
          for (int e = 0; e < 4; e++) {
            int p = 12288*s - 5 + 4*g + e;
            float vv = 0.f;
            if (s == 0) { if (p >= 0) vv = x0d - xs[14 - p]; }
            else        { if (p < TP0) vv = xld - xs[96012 - p]; }
            if (e == 0) v.x = vv; else if (e == 1) v.y = vv;
            else if (e == 2) v.z = vv; else v.w = vv;
          }
        }
        U4[g + g/12] = v;
      }
    }
    if (s < 3) {   // pre-issue next section — stays in flight across barriers
#pragma unroll
      for (int j = 0; j < 4; j++) {
        int g = 1024*j + c;
        if (g < 3074) { int m = min(max(3072*(s+1) - 5 + g, 0), 11999); R[j] = xs4[m]; }
      }
    }
    BAR_LDS();                 // publish staged LDS writes (no vmcnt drain!)
    if ((c >> 8) == s) {
      const int cl = c & 255;
      float4 F[14];
#pragma unroll
      for (int k = 0; k < 14; k++)
        F[k] = U4[13*cl + k + (k >= 12 ? 1 : 0)];
      w4v = F[0].y; w3v = F[0].z; w2v = F[0].w; w1v = F[1].x;
#pragma unroll
      for (int n = 0; n < LCH; n++) A[n] = fget(F[(n + 5) >> 2], (n + 5) & 3);
    }
  }
  BAR_LDS();   // extraction reads done before scan overwrites U

  // ---------- forward phase 1 (in place, zero-state)
  float r1 = 0.f, r2 = 0.f, r3 = 0.f, r4 = 0.f;
#pragma unroll
  for (int n = 0; n < LCH; n++) {
    float xv = A[n];
    float f = fmaf(b0,xv, fmaf(b1,w1v, fmaf(b2,w2v, fmaf(b3,w3v, b4*w4v))));
    w4v = w3v; w3v = w2v; w2v = w1v; w1v = xv;
    float u = fmaf(na4, r4, f);
    u = fmaf(na3, r3, u); u = fmaf(na2, r2, u); u = fmaf(na1, r1, u);
    A[n] = u; r4 = r3; r3 = r2; r2 = r1; r1 = u;
  }

  // ---------- forward chunk-scan (ping-pong float4)
  float4* Sb0 = U4;
  float4* Sb1 = U4 + 1024;
  Sb0[c] = make_float4(r1, r2, r3, r4);
  BAR_LDS();
#pragma unroll
  for (int k = 0; k < 10; k++) {
    float4* cur = (k & 1) ? Sb1 : Sb0;
    float4* nxt = (k & 1) ? Sb0 : Sb1;
    const int off = 1 << k;
    float4 t = cur[c];
    if (c >= off) {
      float4 q = cur[c - off];
      t.x += P[k][0]*q.x  + P[k][1]*q.y  + P[k][2]*q.z  + P[k][3]*q.w;
      t.y += P[k][4]*q.x  + P[k][5]*q.y  + P[k][6]*q.z  + P[k][7]*q.w;
      t.z += P[k][8]*q.x  + P[k][9]*q.y  + P[k][10]*q.z + P[k][11]*q.w;
      t.w += P[k][12]*q.x + P[k][13]*q.y + P[k][14]*q.z + P[k][15]*q.w;
    }
    nxt[c] = t;
    BAR_LDS();
  }
  float4 sv = make_float4(0.f,0.f,0.f,0.f);
  if (c > 0) sv = Sb0[c-1];

  // ---------- forward phase 2: homogeneous correction
  {
    float h1 = sv.x, h2 = sv.y, h3 = sv.z, h4 = sv.w;
#pragma unroll
    for (int n = 0; n < LCH; n++) {
      float h = fmaf(na1, h1, fmaf(na2, h2, fmaf(na3, h3, na4 * h4)));
      A[n] += h;
      h4 = h3; h3 = h2; h2 = h1; h1 = h;
    }
  }
  // exact zero tail past TP0
  if (c >= 1000) {
#pragma unroll
    for (int n = 0; n < LCH; n++) if (48*c + n >= TP0) A[n] = 0.f;
  }

  // ---------- exchange heads (backward FIR halo)
  Sb1[c] = make_float4(A[0], A[1], A[2], A[3]);
  BAR_LDS();
  float h0 = 0.f, h1v = 0.f, h2v = 0.f, h3v = 0.f;
  if (c < NCH - 1) { float4 hv = Sb1[c+1]; h0 = hv.x; h1v = hv.y; h2v = hv.z; h3v = hv.w; }

  // ---------- backward phase 1 (own chunk reversed, in place)
#define YV(i) ((i) < 48 ? A[(i)] : ((i)==48 ? h0 : (i)==49 ? h1v : (i)==50 ? h2v : h3v))
  r1 = 0.f; r2 = 0.f; r3 = 0.f; r4 = 0.f;
#pragma unroll
  for (int m = 0; m < LCH; m++) {
    float g = fmaf(b0, YV(47-m), fmaf(b1, YV(48-m),
              fmaf(b2, YV(49-m), fmaf(b3, YV(50-m), b4 * YV(51-m)))));
    float u = fmaf(na4, r4, g);
    u = fmaf(na3, r3, u); u = fmaf(na2, r2, u); u = fmaf(na1, r1, u);
    r4 = r3; r3 = r2; r2 = r1; r1 = u;
    if      (m == 0) h3v = u;
    else if (m == 1) h2v = u;
    else if (m == 2) h1v = u;
    else if (m == 3) h0  = u;
    else             A[51 - m] = u;
  }
#undef YV
  // z[0]=h3v z[1]=h2v z[2]=h1v z[3]=h0 ; z[m]=A[51-m] for m>=4

  // ---------- backward chunk-scan
  const int d = NCH - 1 - c;
  Sb0[d] = make_float4(r1, r2, r3, r4);
  BAR_LDS();
#pragma unroll
  for (int k = 0; k < 10; k++) {
    float4* cur = (k & 1) ? Sb1 : Sb0;
    float4* nxt = (k & 1) ? Sb0 : Sb1;
    const int off = 1 << k;
    float4 t = cur[d];
    if (d >= off) {
      float4 q = cur[d - off];
      t.x += P[k][0]*q.x  + P[k][1]*q.y  + P[k][2]*q.z  + P[k][3]*q.w;
      t.y += P[k][4]*q.x  + P[k][5]*q.y  + P[k][6]*q.z  + P[k][7]*q.w;
      t.z += P[k][8]*q.x  + P[k][9]*q.y  + P[k][10]*q.z + P[k][11]*q.w;
      t.w += P[k][12]*q.x + P[k][13]*q.y + P[k][14]*q.z + P[k][15]*q.w;
    }
    nxt[d] = t;
    BAR_LDS();
  }
  float4 ev = make_float4(0.f,0.f,0.f,0.f);
  if (d > 0) ev = Sb0[d-1];

  // ---------- backward phase 2
  {
    float g1 = ev.x, g2 = ev.y, g3 = ev.z, g4 = ev.w;
#pragma unroll
    for (int m = 0; m < LCH; m++) {
      float h = fmaf(na1, g1, fmaf(na2, g2, fmaf(na3, g3, na4 * g4)));
      if      (m == 0) h3v += h;
      else if (m == 1) h2v += h;
      else if (m == 2) h1v += h;
      else if (m == 3) h0  += h;
      else             A[51 - m] += h;
      g4 = g3; g3 = g2; g2 = g1; g1 = h;
    }
  }

  // ---------- store staging: u = t + 3; thread c owns u4 in [12c-3, 12c+9)
  // slot k4 (u4 = 12c-3+k4) = (z[47-4k4], z[46-4k4], z[45-4k4], z[44-4k4])
  //   = (A[4k4+4..4k4+7]) for k4<=10 ; k4==11 -> (h0, h1v, h2v, h3v)
  BAR_LDS();   // ev reads retired before store-stage writes
  for (int s = 0; s < 4; s++) {
#pragma unroll
    for (int k4 = 0; k4 < 12; k4++) {
      int u4 = 12*c - 3 + k4;
      unsigned lu4 = (unsigned)(u4 - 3000*s);
      if (lu4 <= 3000u) {
        float4 v;
        if (k4 < 11) v = make_float4(A[4*k4+4], A[4*k4+5], A[4*k4+6], A[4*k4+7]);
        else         v = make_float4(h0, h1v, h2v, h3v);
        U4[(int)lu4 + (int)lu4/12] = v;
      }
    }
    BAR_LDS();                 // publish stage writes
#pragma unroll
    for (int j = 0; j < 3; j++) {
      int t4l = 1024*j + c;
      if (t4l < 3000) {
        int q0 = t4l, q1 = t4l + 1;
        int a0 = 4*(q0 + q0/12) + 3;
        int bi = 4*(q1 + q1/12);
        float4 v;
        v.x = U[a0]; v.y = U[bi]; v.z = U[bi+1]; v.w = U[bi+2];
        os4[3000*s + t4l] = v;   // fire-and-forget: no vmcnt wait, ever
      }
    }
    if (s < 3) BAR_LDS();      // readback ds_reads retired before next stage
  }
}

extern "C" void kernel_launch(void* const* d_in, const int* in_sizes, int n_in,
                              void* d_out, int out_size, void* d_ws, size_t ws_size,
                              hipStream_t stream) {
  (void)n_in; (void)d_ws; (void)ws_size; (void)out_size;
  const float* x = (const float*)d_in[0];
  const float* b = (const float*)d_in[1];
  const float* a = (const float*)d_in[2];
  float* out = (float*)d_out;
  const int nseq = in_sizes[0] / T48;   // 512
  filtfilt_k<<<dim3(nseq), dim3(1024), 0, stream>>>(x, b, a, out);
}